// Round 4
// baseline (435.270 us; speedup 1.0000x reference)
//
#include <hip/hip_runtime.h>

// LengthRegulator: B=64, T=512, D=384, MAX_LEN=4096
// R6: occupancy-targeted restructure of R5's fused kernel.
//   Evidence: R4->R5 removed ~1200 prologue cycles/block and showed ~1:1 in wall
//   time -> prologues are NOT hidden -> too few resident blocks/CU (deep-unrolled
//   float4 loop => high VGPR => 1-2 blocks/CU at BLOCK=512).
//   Changes: BLOCK 512->256 (4-wave blocks), __launch_bounds__(256,8) caps VGPR
//   at 64 -> 8 blocks/CU = 32 waves (full occupancy); copy loop ITER=24 with
//   partial unroll 6 to keep in-flight regs low; scan handles 2 durations/thread.
// Swizzle: blockIdx%8 == b%8 pins each batch's x slice to one XCD's L2/L3 path.
// Output layout (flat float32): [B*ML*D] out, then [B] mel_len (as float).

#define T_DIM 512
#define D_DIM 384
#define D4    (D_DIM / 4)   // 96 float4 per row
#define ROWS  64            // output rows per block
#define BLOCK 256
#define ITER  ((ROWS * D4) / BLOCK)  // 24
#define NWAVE (BLOCK / 64)  // 4

typedef float vfloat4 __attribute__((ext_vector_type(4)));

__global__ __launch_bounds__(BLOCK, 8) void lr_fused_kernel(
    const float* __restrict__ x,         // [B, T, D]
    const int*   __restrict__ duration,  // [B, T]
    float*       __restrict__ out,       // [B, ML, D] + [B] mel tail
    int B, int ML)
{
    __shared__ int s_wsum[NWAVE];
    __shared__ int s_idx[ROWS];

    const int b     = blockIdx.x % B;   // XCD = blockIdx % 8 == b % 8
    const int chunk = blockIdx.x / B;
    const int row0  = chunk * ROWS;
    const int tid   = threadIdx.x;
    const int lane  = tid & 63;
    const int wid   = tid >> 6;

    // ---- inclusive scan of duration[b,:]: 2 tokens/thread, shfl scan + fixup ----
    const int2 dd = *(const int2*)(duration + b * T_DIM + 2 * tid);
    const int s  = dd.x + dd.y;
    int v = s;
    #pragma unroll
    for (int off = 1; off < 64; off <<= 1) {
        int u = __shfl_up(v, off);
        if (lane >= off) v += u;
    }
    if (lane == 63) s_wsum[wid] = v;     // wave totals
    if (tid < ROWS) s_idx[tid] = -1;     // init window to "masked"
    __syncthreads();

    int wprefix = 0, mel = 0;
    #pragma unroll
    for (int w = 0; w < NWAVE; ++w) {
        const int t = s_wsum[w];
        if (w < wid) wprefix += t;
        mel += t;
    }
    const int base = wprefix + v - s;    // exclusive csum before token 2*tid
    const int e0   = base + dd.x;        // token 2*tid   owns [base, e0)
    const int e1   = e0 + dd.y;          // token 2*tid+1 owns [e0, e1)

    // ---- scatter overlap with this block's window [row0, row0+ROWS) ----
    {
        int lo = base > row0 ? base : row0;
        int hi = e0 < row0 + ROWS ? e0 : row0 + ROWS;
        for (int p = lo; p < hi; ++p) s_idx[p - row0] = 2 * tid;
        lo = e0 > row0 ? e0 : row0;
        hi = e1 < row0 + ROWS ? e1 : row0 + ROWS;
        for (int p = lo; p < hi; ++p) s_idx[p - row0] = 2 * tid + 1;
    }
    __syncthreads();

    if (chunk == 0 && tid == 0)
        out[(long long)B * ML * D_DIM + b] = (float)mel;

    // ---- gather copy: 64 rows x 384 floats, float4 lanes ----
    const vfloat4* __restrict__ x4   = (const vfloat4*)x;
    vfloat4*       __restrict__ out4 = (vfloat4*)out;
    const long long out_base = ((long long)b * ML + row0) * D4;
    const long long x_base   = (long long)b * T_DIM * D4;

    #pragma unroll 6
    for (int i = 0; i < ITER; ++i) {
        const int flat = tid + i * BLOCK;
        const int r = flat / D4;            // constant divisor -> magic mul
        const int j = flat - r * D4;
        const int t = s_idx[r];             // LDS broadcast
        vfloat4 vv = (vfloat4)(0.f, 0.f, 0.f, 0.f);
        if (t >= 0) vv = x4[x_base + (long long)t * D4 + j];
        out4[out_base + flat] = vv;         // plain store (nt was A/B'd out in R2)
    }
}

extern "C" void kernel_launch(void* const* d_in, const int* in_sizes, int n_in,
                              void* d_out, int out_size, void* d_ws, size_t ws_size,
                              hipStream_t stream) {
    const float* x   = (const float*)d_in[0];
    const int*   dur = (const int*)d_in[1];
    float*       out = (float*)d_out;
    (void)d_ws; (void)ws_size;

    const int B  = in_sizes[1] / T_DIM;                 // 64
    const int ML = (out_size - B) / (B * D_DIM);        // 4096

    const int grid = B * (ML / ROWS);                   // 4096 blocks
    hipLaunchKernelGGL(lr_fused_kernel, dim3(grid), dim3(BLOCK), 0, stream,
                       x, dur, out, B, ML);
}